// Round 1
// baseline (349.884 us; speedup 1.0000x reference)
//
#include <hip/hip_runtime.h>
#include <stdint.h>

// Pipeline: cvt(fp32->bf16) -> gemm_qkv(bf16 MFMA, scatter Q/K [BH][S][D], V^T [BH][D][S])
//           -> rope tables -> rope(Q,K, fold 1/sqrt(128) into Q)
//           -> causal flash attention (bf16 MFMA, online softmax)
//           -> out = Ao @ Wo^T (fp32 epilogue into d_out)
// ws layout (bytes): xb 16M | wqkvb 24M | wob 8M | Q 16M | K 16M | Vt 16M | ctab .5M | stab .5M
// Ao aliases xb (dead after gemm_qkv). Total ~101.7 MB.

#define SCALE_Q 0.08838834764831845f

typedef short bf16x8 __attribute__((ext_vector_type(8)));   // 8 bf16 (4 VGPRs) per guide §3
typedef float f32x4 __attribute__((ext_vector_type(4)));
typedef unsigned short u16x4v __attribute__((ext_vector_type(4)));
typedef unsigned short u16x8v __attribute__((ext_vector_type(8)));

__device__ __forceinline__ unsigned short f2bf(float f) {
  unsigned u = __float_as_uint(f);
  return (unsigned short)((u + 0x7FFFu + ((u >> 16) & 1u)) >> 16);  // RNE
}
__device__ __forceinline__ float bf2f(unsigned short h) {
  return __uint_as_float(((unsigned)h) << 16);
}
__device__ __forceinline__ void gld16(void* lds, const void* g) {
  __builtin_amdgcn_global_load_lds(
      (const __attribute__((address_space(1))) unsigned int*)g,
      (__attribute__((address_space(3))) unsigned int*)lds, 16, 0, 0);
}

// ---------------- fp32 -> bf16 conversion (5 regions via blockIdx.y) ----------------
__global__ __launch_bounds__(256) void cvt_all(
    const float* __restrict__ x, const float* __restrict__ wq,
    const float* __restrict__ wk, const float* __restrict__ wv,
    const float* __restrict__ wo,
    unsigned short* __restrict__ xb, unsigned short* __restrict__ wqkv,
    unsigned short* __restrict__ wob) {
  int r = blockIdx.y;
  size_t i = ((size_t)blockIdx.x * 256 + threadIdx.x) * 8;
  const float* src; unsigned short* dst; size_t n;
  if (r == 0)      { src = x;  dst = xb;             n = 8388608; }
  else if (r == 1) { src = wq; dst = wqkv;           n = 4194304; }
  else if (r == 2) { src = wk; dst = wqkv + 4194304; n = 4194304; }
  else if (r == 3) { src = wv; dst = wqkv + 8388608; n = 4194304; }
  else             { src = wo; dst = wob;            n = 4194304; }
  if (i >= n) return;
  float4 a = *(const float4*)(src + i);
  float4 b = *(const float4*)(src + i + 4);
  u16x8v o;
  o[0] = f2bf(a.x); o[1] = f2bf(a.y); o[2] = f2bf(a.z); o[3] = f2bf(a.w);
  o[4] = f2bf(b.x); o[5] = f2bf(b.y); o[6] = f2bf(b.z); o[7] = f2bf(b.w);
  *(u16x8v*)(dst + i) = o;
}

// ---------------- RoPE tables: ctab/stab[s*64 + j] = cos/sin(s * 10000^(-j/64)) ----------------
__global__ __launch_bounds__(256) void rope_table(float* __restrict__ ct, float* __restrict__ st) {
  int id = blockIdx.x * 256 + threadIdx.x;  // 131072 = 2048*64
  int s = id >> 6, j = id & 63;
  float inv = __powf(10000.0f, -(float)j * (1.0f / 64.0f));
  float a = (float)s * inv;
  ct[id] = __cosf(a);
  st[id] = __sinf(a);
}

// ---------------- 128x128x(BK=64) bf16 GEMM, A[M][K] @ B[N][K]^T (m97 structure) ----------------
// LDS tiles row-major [128][64] bf16 (128B rows), 16B slots XOR-swizzled: phys p = sl ^ (row&7).
// Staged linearly via global_load_lds with pre-swizzled global source (both-sides rule #21).
// MODE 0: scatter epilogue -> Q,K as [BH][S][128] bf16 and V^T as [BH][128][S] bf16.
// MODE 1: fp32 epilogue C0[row*N + col].
template <int MODE>
__global__ __launch_bounds__(256) void gemm_bt(
    const unsigned short* __restrict__ A, const unsigned short* __restrict__ B,
    void* __restrict__ C0, void* __restrict__ C1, void* __restrict__ C2,
    int N, int Kd) {
  __shared__ unsigned short As[128 * 64];
  __shared__ unsigned short Bs[128 * 64];
  const int t = threadIdx.x;
  const int lane = t & 63, w = t >> 6;
  const int g = lane >> 4, c15 = lane & 15;
  const int wr = w >> 1, wc = w & 1;
  const int brow = blockIdx.y * 128, bcol = blockIdx.x * 128;
  const int srow = t >> 3;                  // staging row within each 32-row chunk
  const int ssl = (t & 7) ^ (srow & 7);     // logical slot for physical slot t&7
  const unsigned short* pA = A + (size_t)(brow + srow) * Kd + ssl * 8;
  const unsigned short* pB = B + (size_t)(bcol + srow) * Kd + ssl * 8;

  int aoff[4][2], boff[4][2];
#pragma unroll
  for (int mi = 0; mi < 4; ++mi)
#pragma unroll
    for (int kk = 0; kk < 2; ++kk) {
      int arow = wr * 64 + mi * 16 + c15;
      int bcolr = wc * 64 + mi * 16 + c15;
      int p = (kk * 4 + g) ^ (c15 & 7);     // row&7 == c15&7
      aoff[mi][kk] = arow * 128 + (p << 4);
      boff[mi][kk] = bcolr * 128 + (p << 4);
    }
  f32x4 zero4 = {0.f, 0.f, 0.f, 0.f};
  f32x4 acc[4][4];
#pragma unroll
  for (int a_ = 0; a_ < 4; ++a_)
#pragma unroll
    for (int b_ = 0; b_ < 4; ++b_) acc[a_][b_] = zero4;

  const int nk = Kd >> 6;
  for (int kt = 0; kt < nk; ++kt) {
    const unsigned short* a0 = pA + kt * 64;
    const unsigned short* b0 = pB + kt * 64;
#pragma unroll
    for (int c = 0; c < 4; ++c) {
      gld16((char*)As + c * 4096 + t * 16, a0 + (size_t)c * 32 * Kd);
      gld16((char*)Bs + c * 4096 + t * 16, b0 + (size_t)c * 32 * Kd);
    }
    __syncthreads();  // compiler drains vmcnt(0) before s_barrier (m97 pattern)
    bf16x8 af[4][2], bfv[4][2];
#pragma unroll
    for (int mi = 0; mi < 4; ++mi)
#pragma unroll
      for (int kk = 0; kk < 2; ++kk) {
        af[mi][kk] = *(const bf16x8*)((const char*)As + aoff[mi][kk]);
        bfv[mi][kk] = *(const bf16x8*)((const char*)Bs + boff[mi][kk]);
      }
#pragma unroll
    for (int mi = 0; mi < 4; ++mi)
#pragma unroll
      for (int nj = 0; nj < 4; ++nj)
#pragma unroll
        for (int kk = 0; kk < 2; ++kk)
          acc[mi][nj] = __builtin_amdgcn_mfma_f32_16x16x32_bf16(
              af[mi][kk], bfv[nj][kk], acc[mi][nj], 0, 0, 0);
    __syncthreads();
  }

  // Epilogue. C/D layout: col = lane&15, row = (lane>>4)*4 + i  [m89]
#pragma unroll
  for (int mi = 0; mi < 4; ++mi) {
#pragma unroll
    for (int nj = 0; nj < 4; ++nj) {
      f32x4 v = acc[mi][nj];
      int row0 = brow + wr * 64 + mi * 16 + g * 4;
      int col = bcol + wc * 64 + nj * 16 + c15;
      if (MODE == 0) {
        int which = col >> 11;            // 0=Q 1=K 2=V
        int hc = col & 2047;
        int bh = ((row0 >> 11) << 4) + (hc >> 7);
        int d = hc & 127, s0 = row0 & 2047;
        if (which == 2) {                 // V^T: [bh][d][s], i-values are s-contiguous
          u16x4v pk;
          pk[0] = f2bf(v[0]); pk[1] = f2bf(v[1]); pk[2] = f2bf(v[2]); pk[3] = f2bf(v[3]);
          *(u16x4v*)((unsigned short*)C2 + ((size_t)bh * 128 + d) * 2048 + s0) = pk;
        } else {
          unsigned short* dst =
              (unsigned short*)(which ? C1 : C0) + ((size_t)bh * 2048 + s0) * 128 + d;
#pragma unroll
          for (int i = 0; i < 4; ++i) dst[(size_t)i * 128] = f2bf(v[i]);
        }
      } else {
        float* Cf = (float*)C0;
#pragma unroll
        for (int i = 0; i < 4; ++i) Cf[(size_t)(row0 + i) * N + col] = v[i];
      }
    }
  }
}

// ---------------- RoPE (in-place on bf16 Q,K [BH][S][128]); Q gets 1/sqrt(128) folded ----------------
__global__ __launch_bounds__(256) void rope_apply(
    unsigned short* __restrict__ Q, unsigned short* __restrict__ K,
    const float* __restrict__ ct, const float* __restrict__ st) {
  int id = blockIdx.x * 256 + threadIdx.x;  // 524288 = 32*2048*8
  int o = id & 7;
  int s = (id >> 3) & 2047;
  int bh = id >> 14;
  size_t base = ((size_t)bh * 2048 + s) * 128 + o * 8;
  u16x8v qlo = *(u16x8v*)(Q + base), qhi = *(u16x8v*)(Q + base + 64);
  u16x8v klo = *(u16x8v*)(K + base), khi = *(u16x8v*)(K + base + 64);
  const float* cp = ct + s * 64 + o * 8;
  const float* sp = st + s * 64 + o * 8;
#pragma unroll
  for (int j = 0; j < 8; ++j) {
    float c = cp[j], sn = sp[j];
    float ql = bf2f(qlo[j]), qh = bf2f(qhi[j]);
    qlo[j] = f2bf((ql * c - qh * sn) * SCALE_Q);
    qhi[j] = f2bf((qh * c + ql * sn) * SCALE_Q);
    float kl = bf2f(klo[j]), kh = bf2f(khi[j]);
    klo[j] = f2bf(kl * c - kh * sn);
    khi[j] = f2bf(kh * c + kl * sn);
  }
  *(u16x8v*)(Q + base) = qlo; *(u16x8v*)(Q + base + 64) = qhi;
  *(u16x8v*)(K + base) = klo; *(u16x8v*)(K + base + 64) = khi;
}

// ---------------- causal flash attention: QBLK=64 (16 rows/wave), KVB=64 ----------------
// Ks [kv][128d] 256B rows, 16 slots, swz p = sl ^ (row&15); Vs = V^T [d][64kv] 128B rows, swz p = sl ^ (row&7).
__global__ __launch_bounds__(256) void attn_fwd(
    const unsigned short* __restrict__ Qg, const unsigned short* __restrict__ Kg,
    const unsigned short* __restrict__ Vtg, unsigned short* __restrict__ Og) {
  __shared__ unsigned short Ks[64 * 128];
  __shared__ unsigned short Vs[128 * 64];
  __shared__ unsigned short Pl[4][16 * 88];  // per-wave P^T buffer, stride 88 (176B, 16B-mult, 2-way banks)
  const int t = threadIdx.x;
  const int lane = t & 63, w = t >> 6;
  const int g = lane >> 4, c15 = lane & 15;
  const int qb = (int)gridDim.x - 1 - (int)blockIdx.x;  // heavy blocks dispatch first
  const int bh = blockIdx.y;
  const int q0 = qb * 64;
  const int qrow = q0 + w * 16;

  bf16x8 qf[4];
  {
    const unsigned short* qp = Qg + ((size_t)bh * 2048 + qrow + c15) * 128 + g * 8;
#pragma unroll
    for (int kf = 0; kf < 4; ++kf) qf[kf] = *(const bf16x8*)(qp + kf * 32);
  }
  f32x4 zero4 = {0.f, 0.f, 0.f, 0.f};
  f32x4 o[8];
#pragma unroll
  for (int db = 0; db < 8; ++db) o[db] = zero4;
  float mrow[4] = {-1e30f, -1e30f, -1e30f, -1e30f};
  float lrow[4] = {0.f, 0.f, 0.f, 0.f};

  const int ksrow = t >> 4;                       // K stage: 16 threads/256B row
  const int kssl = (t & 15) ^ ksrow;
  const unsigned short* kp = Kg + ((size_t)bh * 2048 + ksrow) * 128 + kssl * 8;
  const int vsrow = t >> 3;                       // V stage: 8 threads/128B row
  const int vssl = (t & 7) ^ (vsrow & 7);
  const unsigned short* vp = Vtg + ((size_t)bh * 128 + vsrow) * 2048 + vssl * 8;

  const int nt = qb + 1;
  for (int tkv = 0; tkv < nt; ++tkv) {
#pragma unroll
    for (int c = 0; c < 4; ++c) {
      gld16((char*)Ks + c * 4096 + t * 16, kp + (size_t)(tkv * 64 + c * 16) * 128);
      gld16((char*)Vs + c * 4096 + t * 16, vp + (size_t)c * 32 * 2048 + tkv * 64);
    }
    __syncthreads();

    // S = Q K^T  (rows q, cols kv)
    f32x4 sv[4];
#pragma unroll
    for (int cb = 0; cb < 4; ++cb) {
      f32x4 z = zero4;
#pragma unroll
      for (int kf = 0; kf < 4; ++kf) {
        int row = cb * 16 + c15;
        int p = (kf * 4 + g) ^ c15;
        bf16x8 kfr = *(const bf16x8*)((const char*)Ks + row * 256 + p * 16);
        z = __builtin_amdgcn_mfma_f32_16x16x32_bf16(qf[kf], kfr, z, 0, 0, 0);
      }
      sv[cb] = z;
    }
    if (tkv == qb) {  // diagonal tile causal mask
#pragma unroll
      for (int cb = 0; cb < 4; ++cb)
#pragma unroll
        for (int i = 0; i < 4; ++i) {
          int colk = q0 + cb * 16 + c15;
          int rq = qrow + g * 4 + i;
          if (colk > rq) sv[cb][i] = -1e30f;
        }
    }
    // online softmax: rows live in 16-lane groups, reduce over lane&15
    float pmx[4];
#pragma unroll
    for (int i = 0; i < 4; ++i)
      pmx[i] = fmaxf(fmaxf(sv[0][i], sv[1][i]), fmaxf(sv[2][i], sv[3][i]));
#pragma unroll
    for (int dd = 1; dd < 16; dd <<= 1)
#pragma unroll
      for (int i = 0; i < 4; ++i) pmx[i] = fmaxf(pmx[i], __shfl_xor(pmx[i], dd));
    float sc[4], psum[4];
#pragma unroll
    for (int i = 0; i < 4; ++i) {
      float nm = fmaxf(mrow[i], pmx[i]);
      sc[i] = __expf(mrow[i] - nm);
      mrow[i] = nm;
      psum[i] = 0.f;
    }
#pragma unroll
    for (int cb = 0; cb < 4; ++cb)
#pragma unroll
      for (int i = 0; i < 4; ++i) {
        float e = __expf(sv[cb][i] - mrow[i]);
        sv[cb][i] = e;
        psum[i] += e;
      }
#pragma unroll
    for (int dd = 1; dd < 16; dd <<= 1)
#pragma unroll
      for (int i = 0; i < 4; ++i) psum[i] += __shfl_xor(psum[i], dd);
#pragma unroll
    for (int i = 0; i < 4; ++i) lrow[i] = lrow[i] * sc[i] + psum[i];
#pragma unroll
    for (int db = 0; db < 8; ++db)
#pragma unroll
      for (int i = 0; i < 4; ++i) o[db][i] *= sc[i];

    // P: C-layout -> A-layout via per-wave LDS (in-wave, waits compiler-inserted)
    unsigned short* pw = &Pl[w][0];
#pragma unroll
    for (int cb = 0; cb < 4; ++cb)
#pragma unroll
      for (int i = 0; i < 4; ++i)
        pw[(g * 4 + i) * 88 + cb * 16 + c15] = f2bf(sv[cb][i]);
    bf16x8 pf[2];
#pragma unroll
    for (int kb = 0; kb < 2; ++kb)
      pf[kb] = *(const bf16x8*)((const char*)pw + c15 * 176 + kb * 64 + g * 16);

    // O += P V  (B-frag of V from V^T: per-lane contiguous 16B)
#pragma unroll
    for (int db = 0; db < 8; ++db) {
#pragma unroll
      for (int kb = 0; kb < 2; ++kb) {
        int row = db * 16 + c15;
        int p = (kb * 4 + g) ^ (c15 & 7);
        bf16x8 vfr = *(const bf16x8*)((const char*)Vs + row * 128 + p * 16);
        o[db] = __builtin_amdgcn_mfma_f32_16x16x32_bf16(pf[kb], vfr, o[db], 0, 0, 0);
      }
    }
    __syncthreads();
  }

  const int b = bh >> 4, h = bh & 15;
  float linv[4];
#pragma unroll
  for (int i = 0; i < 4; ++i) linv[i] = 1.0f / lrow[i];
#pragma unroll
  for (int db = 0; db < 8; ++db)
#pragma unroll
    for (int i = 0; i < 4; ++i) {
      int q = qrow + g * 4 + i;
      Og[((size_t)(b * 2048 + q)) * 2048 + h * 128 + db * 16 + c15] =
          f2bf(o[db][i] * linv[i]);
    }
}

extern "C" void kernel_launch(void* const* d_in, const int* in_sizes, int n_in,
                              void* d_out, int out_size, void* d_ws, size_t ws_size,
                              hipStream_t stream) {
  const float* x  = (const float*)d_in[0];
  const float* Wq = (const float*)d_in[1];
  const float* Wk = (const float*)d_in[2];
  const float* Wv = (const float*)d_in[3];
  const float* Wo = (const float*)d_in[4];
  char* p = (char*)d_ws;
  unsigned short* xb    = (unsigned short*)p;                 // 16 MB (reused as Ao)
  unsigned short* wqkvb = (unsigned short*)(p + 16777216);    // 24 MB
  unsigned short* wob   = (unsigned short*)(p + 41943040);    //  8 MB
  unsigned short* Qb    = (unsigned short*)(p + 50331648);    // 16 MB
  unsigned short* Kb    = (unsigned short*)(p + 67108864);    // 16 MB
  unsigned short* Vt    = (unsigned short*)(p + 83886080);    // 16 MB
  float* ctab           = (float*)(p + 100663296);            // 0.5 MB
  float* stab           = (float*)(p + 101187584);            // 0.5 MB -> end 101711872
  unsigned short* Ao = xb;  // xb dead after gemm_qkv

  cvt_all<<<dim3(4096, 5), 256, 0, stream>>>(x, Wq, Wk, Wv, Wo, xb, wqkvb, wob);
  rope_table<<<512, 256, 0, stream>>>(ctab, stab);
  gemm_bt<0><<<dim3(48, 32), 256, 0, stream>>>(xb, wqkvb, Qb, Kb, Vt, 6144, 2048);
  rope_apply<<<2048, 256, 0, stream>>>(Qb, Kb, ctab, stab);
  attn_fwd<<<dim3(32, 32), 256, 0, stream>>>(Qb, Kb, Vt, Ao);
  gemm_bt<1><<<dim3(16, 32), 256, 0, stream>>>(Ao, wob, d_out, nullptr, nullptr, 2048, 2048);
}

// Round 2
// 293.540 us; speedup vs baseline: 1.1919x; 1.1919x over previous
//
#include <hip/hip_runtime.h>
#include <stdint.h>

// Pipeline: cvt(fp32->bf16) -> gemm_qkv(bf16 MFMA, scatter Q/K [BH][S][D], V^T [BH][D][S])
//           -> rope tables -> rope(Q,K, fold 1/sqrt(128) into Q)
//           -> causal flash attention (bf16 MFMA, online softmax, paired q-blocks + dbuf)
//           -> out = Ao @ Wo^T (fp32 epilogue into d_out)
// ws layout (bytes): xb 16M | wqkvb 24M | wob 8M | Q 16M | K 16M | Vt 16M | ctab .5M | stab .5M
// Ao aliases xb (dead after gemm_qkv). Total ~101.7 MB.

#define SCALE_Q 0.08838834764831845f

typedef short bf16x8 __attribute__((ext_vector_type(8)));   // 8 bf16 (4 VGPRs) per guide §3
typedef float f32x4 __attribute__((ext_vector_type(4)));
typedef unsigned short u16x4v __attribute__((ext_vector_type(4)));
typedef unsigned short u16x8v __attribute__((ext_vector_type(8)));

__device__ __forceinline__ unsigned short f2bf(float f) {
  unsigned u = __float_as_uint(f);
  return (unsigned short)((u + 0x7FFFu + ((u >> 16) & 1u)) >> 16);  // RNE
}
__device__ __forceinline__ float bf2f(unsigned short h) {
  return __uint_as_float(((unsigned)h) << 16);
}
__device__ __forceinline__ void gld16(void* lds, const void* g) {
  __builtin_amdgcn_global_load_lds(
      (const __attribute__((address_space(1))) unsigned int*)g,
      (__attribute__((address_space(3))) unsigned int*)lds, 16, 0, 0);
}

// ---------------- fp32 -> bf16 conversion (5 regions via blockIdx.y) ----------------
__global__ __launch_bounds__(256) void cvt_all(
    const float* __restrict__ x, const float* __restrict__ wq,
    const float* __restrict__ wk, const float* __restrict__ wv,
    const float* __restrict__ wo,
    unsigned short* __restrict__ xb, unsigned short* __restrict__ wqkv,
    unsigned short* __restrict__ wob) {
  int r = blockIdx.y;
  size_t i = ((size_t)blockIdx.x * 256 + threadIdx.x) * 8;
  const float* src; unsigned short* dst; size_t n;
  if (r == 0)      { src = x;  dst = xb;             n = 8388608; }
  else if (r == 1) { src = wq; dst = wqkv;           n = 4194304; }
  else if (r == 2) { src = wk; dst = wqkv + 4194304; n = 4194304; }
  else if (r == 3) { src = wv; dst = wqkv + 8388608; n = 4194304; }
  else             { src = wo; dst = wob;            n = 4194304; }
  if (i >= n) return;
  float4 a = *(const float4*)(src + i);
  float4 b = *(const float4*)(src + i + 4);
  u16x8v o;
  o[0] = f2bf(a.x); o[1] = f2bf(a.y); o[2] = f2bf(a.z); o[3] = f2bf(a.w);
  o[4] = f2bf(b.x); o[5] = f2bf(b.y); o[6] = f2bf(b.z); o[7] = f2bf(b.w);
  *(u16x8v*)(dst + i) = o;
}

// ---------------- RoPE tables: ctab/stab[s*64 + j] = cos/sin(s * 10000^(-j/64)) ----------------
__global__ __launch_bounds__(256) void rope_table(float* __restrict__ ct, float* __restrict__ st) {
  int id = blockIdx.x * 256 + threadIdx.x;  // 131072 = 2048*64
  int s = id >> 6, j = id & 63;
  float inv = __powf(10000.0f, -(float)j * (1.0f / 64.0f));
  float a = (float)s * inv;
  ct[id] = __cosf(a);
  st[id] = __sinf(a);
}

// ---------------- 128x128x(BK=64) bf16 GEMM, A[M][K] @ B[N][K]^T (m97 structure) ----------------
// LDS tiles row-major [128][64] bf16 (128B rows), 16B slots XOR-swizzled: phys p = sl ^ (row&7).
// Staged linearly via global_load_lds with pre-swizzled global source (both-sides rule #21).
// MODE 0: scatter epilogue -> Q,K as [BH][S][128] bf16 and V^T as [BH][128][S] bf16.
// MODE 1: fp32 epilogue C0[row*N + col].
template <int MODE>
__global__ __launch_bounds__(256) void gemm_bt(
    const unsigned short* __restrict__ A, const unsigned short* __restrict__ B,
    void* __restrict__ C0, void* __restrict__ C1, void* __restrict__ C2,
    int N, int Kd) {
  __shared__ unsigned short As[128 * 64];
  __shared__ unsigned short Bs[128 * 64];
  const int t = threadIdx.x;
  const int lane = t & 63, w = t >> 6;
  const int g = lane >> 4, c15 = lane & 15;
  const int wr = w >> 1, wc = w & 1;
  const int brow = blockIdx.y * 128, bcol = blockIdx.x * 128;
  const int srow = t >> 3;                  // staging row within each 32-row chunk
  const int ssl = (t & 7) ^ (srow & 7);     // logical slot for physical slot t&7
  const unsigned short* pA = A + (size_t)(brow + srow) * Kd + ssl * 8;
  const unsigned short* pB = B + (size_t)(bcol + srow) * Kd + ssl * 8;

  int aoff[4][2], boff[4][2];
#pragma unroll
  for (int mi = 0; mi < 4; ++mi)
#pragma unroll
    for (int kk = 0; kk < 2; ++kk) {
      int arow = wr * 64 + mi * 16 + c15;
      int bcolr = wc * 64 + mi * 16 + c15;
      int p = (kk * 4 + g) ^ (c15 & 7);     // row&7 == c15&7
      aoff[mi][kk] = arow * 128 + (p << 4);
      boff[mi][kk] = bcolr * 128 + (p << 4);
    }
  f32x4 zero4 = {0.f, 0.f, 0.f, 0.f};
  f32x4 acc[4][4];
#pragma unroll
  for (int a_ = 0; a_ < 4; ++a_)
#pragma unroll
    for (int b_ = 0; b_ < 4; ++b_) acc[a_][b_] = zero4;

  const int nk = Kd >> 6;
  for (int kt = 0; kt < nk; ++kt) {
    const unsigned short* a0 = pA + kt * 64;
    const unsigned short* b0 = pB + kt * 64;
#pragma unroll
    for (int c = 0; c < 4; ++c) {
      gld16((char*)As + c * 4096 + t * 16, a0 + (size_t)c * 32 * Kd);
      gld16((char*)Bs + c * 4096 + t * 16, b0 + (size_t)c * 32 * Kd);
    }
    __syncthreads();  // compiler drains vmcnt(0) before s_barrier (m97 pattern)
    bf16x8 af[4][2], bfv[4][2];
#pragma unroll
    for (int mi = 0; mi < 4; ++mi)
#pragma unroll
      for (int kk = 0; kk < 2; ++kk) {
        af[mi][kk] = *(const bf16x8*)((const char*)As + aoff[mi][kk]);
        bfv[mi][kk] = *(const bf16x8*)((const char*)Bs + boff[mi][kk]);
      }
#pragma unroll
    for (int mi = 0; mi < 4; ++mi)
#pragma unroll
      for (int nj = 0; nj < 4; ++nj)
#pragma unroll
        for (int kk = 0; kk < 2; ++kk)
          acc[mi][nj] = __builtin_amdgcn_mfma_f32_16x16x32_bf16(
              af[mi][kk], bfv[nj][kk], acc[mi][nj], 0, 0, 0);
    __syncthreads();
  }

  // Epilogue. C/D layout: col = lane&15, row = (lane>>4)*4 + i  [m89]
#pragma unroll
  for (int mi = 0; mi < 4; ++mi) {
#pragma unroll
    for (int nj = 0; nj < 4; ++nj) {
      f32x4 v = acc[mi][nj];
      int row0 = brow + wr * 64 + mi * 16 + g * 4;
      int col = bcol + wc * 64 + nj * 16 + c15;
      if (MODE == 0) {
        int which = col >> 11;            // 0=Q 1=K 2=V
        int hc = col & 2047;
        int bh = ((row0 >> 11) << 4) + (hc >> 7);
        int d = hc & 127, s0 = row0 & 2047;
        if (which == 2) {                 // V^T: [bh][d][s], i-values are s-contiguous
          u16x4v pk;
          pk[0] = f2bf(v[0]); pk[1] = f2bf(v[1]); pk[2] = f2bf(v[2]); pk[3] = f2bf(v[3]);
          *(u16x4v*)((unsigned short*)C2 + ((size_t)bh * 128 + d) * 2048 + s0) = pk;
        } else {
          unsigned short* dst =
              (unsigned short*)(which ? C1 : C0) + ((size_t)bh * 2048 + s0) * 128 + d;
#pragma unroll
          for (int i = 0; i < 4; ++i) dst[(size_t)i * 128] = f2bf(v[i]);
        }
      } else {
        float* Cf = (float*)C0;
#pragma unroll
        for (int i = 0; i < 4; ++i) Cf[(size_t)(row0 + i) * N + col] = v[i];
      }
    }
  }
}

// ---------------- RoPE (in-place on bf16 Q,K [BH][S][128]); Q gets 1/sqrt(128) folded ----------------
__global__ __launch_bounds__(256) void rope_apply(
    unsigned short* __restrict__ Q, unsigned short* __restrict__ K,
    const float* __restrict__ ct, const float* __restrict__ st) {
  int id = blockIdx.x * 256 + threadIdx.x;  // 524288 = 32*2048*8
  int o = id & 7;
  int s = (id >> 3) & 2047;
  int bh = id >> 14;
  size_t base = ((size_t)bh * 2048 + s) * 128 + o * 8;
  u16x8v qlo = *(u16x8v*)(Q + base), qhi = *(u16x8v*)(Q + base + 64);
  u16x8v klo = *(u16x8v*)(K + base), khi = *(u16x8v*)(K + base + 64);
  const float* cp = ct + s * 64 + o * 8;
  const float* sp = st + s * 64 + o * 8;
#pragma unroll
  for (int j = 0; j < 8; ++j) {
    float c = cp[j], sn = sp[j];
    float ql = bf2f(qlo[j]), qh = bf2f(qhi[j]);
    qlo[j] = f2bf((ql * c - qh * sn) * SCALE_Q);
    qhi[j] = f2bf((qh * c + ql * sn) * SCALE_Q);
    float kl = bf2f(klo[j]), kh = bf2f(khi[j]);
    klo[j] = f2bf(kl * c - kh * sn);
    khi[j] = f2bf(kh * c + kl * sn);
  }
  *(u16x8v*)(Q + base) = qlo; *(u16x8v*)(Q + base + 64) = qhi;
  *(u16x8v*)(K + base) = klo; *(u16x8v*)(K + base + 64) = khi;
}

// ---------------- causal flash attention: paired q-blocks (perfect balance) + dbuf K/V ----------------
// Block pair = blockIdx.x handles q-block pair and (31 - pair): exactly 33 KV tiles each.
// 2-phase pipeline: barrier at top, issue next-tile global_load_lds, then compute current.
// Ks [kv][128d] 256B rows, swz p = sl ^ (row&15); Vs = V^T [d][64kv] 128B rows, swz p = sl ^ (row&7).
__global__ __launch_bounds__(256) void attn_fwd(
    const unsigned short* __restrict__ Qg, const unsigned short* __restrict__ Kg,
    const unsigned short* __restrict__ Vtg, unsigned short* __restrict__ Og) {
  __shared__ unsigned short Ks[2][64 * 128];
  __shared__ unsigned short Vs[2][64 * 128];
  __shared__ unsigned short Pl[4][16 * 88];  // per-wave P^T buffer, stride 88
  const int t = threadIdx.x;
  const int lane = t & 63, w = t >> 6;
  const int g = lane >> 4, c15 = lane & 15;
  const int pair = blockIdx.x;
  const int bh = blockIdx.y;
  const int b = bh >> 4, h = bh & 15;

  const int ksrow = t >> 4;                       // K stage: 16 threads/256B row
  const int kssl = (t & 15) ^ ksrow;
  const unsigned short* kp = Kg + ((size_t)bh * 2048 + ksrow) * 128 + kssl * 8;
  const int vsrow = t >> 3;                       // V stage: 8 threads/128B row
  const int vssl = (t & 7) ^ (vsrow & 7);
  const unsigned short* vp = Vtg + ((size_t)bh * 128 + vsrow) * 2048 + vssl * 8;

  auto stageTile = [&](int buf, int tkv) {
#pragma unroll
    for (int c = 0; c < 4; ++c) {
      gld16((char*)Ks[buf] + c * 4096 + t * 16, kp + (size_t)(tkv * 64 + c * 16) * 128);
      gld16((char*)Vs[buf] + c * 4096 + t * 16, vp + (size_t)c * 32 * 2048 + tkv * 64);
    }
  };

  f32x4 zero4 = {0.f, 0.f, 0.f, 0.f};
  f32x4 o[8];
  float mrow[4], lrow[4];
  bf16x8 qf[4];

  auto computeTile = [&](int buf, int qb, int tkv) {
    const int q0 = qb * 64;
    const int qrow = q0 + w * 16;
    // S = Q K^T  (rows q, cols kv)
    f32x4 sv[4];
    __builtin_amdgcn_s_setprio(1);
#pragma unroll
    for (int cb = 0; cb < 4; ++cb) {
      f32x4 z = zero4;
#pragma unroll
      for (int kf = 0; kf < 4; ++kf) {
        int row = cb * 16 + c15;
        int p = (kf * 4 + g) ^ c15;
        bf16x8 kfr = *(const bf16x8*)((const char*)Ks[buf] + row * 256 + p * 16);
        z = __builtin_amdgcn_mfma_f32_16x16x32_bf16(qf[kf], kfr, z, 0, 0, 0);
      }
      sv[cb] = z;
    }
    __builtin_amdgcn_s_setprio(0);
    if (tkv == qb) {  // diagonal tile causal mask
#pragma unroll
      for (int cb = 0; cb < 4; ++cb)
#pragma unroll
        for (int i = 0; i < 4; ++i) {
          int colk = q0 + cb * 16 + c15;
          int rq = qrow + g * 4 + i;
          if (colk > rq) sv[cb][i] = -1e30f;
        }
    }
    // online softmax: rows live in 16-lane groups, reduce over lane&15
    float pmx[4];
#pragma unroll
    for (int i = 0; i < 4; ++i)
      pmx[i] = fmaxf(fmaxf(sv[0][i], sv[1][i]), fmaxf(sv[2][i], sv[3][i]));
#pragma unroll
    for (int dd = 1; dd < 16; dd <<= 1)
#pragma unroll
      for (int i = 0; i < 4; ++i) pmx[i] = fmaxf(pmx[i], __shfl_xor(pmx[i], dd));
    float sc[4], psum[4];
#pragma unroll
    for (int i = 0; i < 4; ++i) {
      float nm = fmaxf(mrow[i], pmx[i]);
      sc[i] = __expf(mrow[i] - nm);
      mrow[i] = nm;
      psum[i] = 0.f;
    }
#pragma unroll
    for (int cb = 0; cb < 4; ++cb)
#pragma unroll
      for (int i = 0; i < 4; ++i) {
        float e = __expf(sv[cb][i] - mrow[i]);
        sv[cb][i] = e;
        psum[i] += e;
      }
#pragma unroll
    for (int dd = 1; dd < 16; dd <<= 1)
#pragma unroll
      for (int i = 0; i < 4; ++i) psum[i] += __shfl_xor(psum[i], dd);
#pragma unroll
    for (int i = 0; i < 4; ++i) lrow[i] = lrow[i] * sc[i] + psum[i];
#pragma unroll
    for (int db = 0; db < 8; ++db)
#pragma unroll
      for (int i = 0; i < 4; ++i) o[db][i] *= sc[i];

    // P: C-layout -> A-layout via per-wave LDS (in-wave, waits compiler-inserted)
    unsigned short* pw = &Pl[w][0];
#pragma unroll
    for (int cb = 0; cb < 4; ++cb)
#pragma unroll
      for (int i = 0; i < 4; ++i)
        pw[(g * 4 + i) * 88 + cb * 16 + c15] = f2bf(sv[cb][i]);
    bf16x8 pf[2];
#pragma unroll
    for (int kb = 0; kb < 2; ++kb)
      pf[kb] = *(const bf16x8*)((const char*)pw + c15 * 176 + kb * 64 + g * 16);

    // O += P V  (B-frag of V from V^T: per-lane contiguous 16B)
    __builtin_amdgcn_s_setprio(1);
#pragma unroll
    for (int db = 0; db < 8; ++db) {
#pragma unroll
      for (int kb = 0; kb < 2; ++kb) {
        int row = db * 16 + c15;
        int p = (kb * 4 + g) ^ (c15 & 7);
        bf16x8 vfr = *(const bf16x8*)((const char*)Vs[buf] + row * 128 + p * 16);
        o[db] = __builtin_amdgcn_mfma_f32_16x16x32_bf16(pf[kb], vfr, o[db], 0, 0, 0);
      }
    }
    __builtin_amdgcn_s_setprio(0);
  };

  auto loadQ = [&](int qb) {
    const unsigned short* qp = Qg + ((size_t)bh * 2048 + qb * 64 + w * 16 + c15) * 128 + g * 8;
#pragma unroll
    for (int kf = 0; kf < 4; ++kf) qf[kf] = *(const bf16x8*)(qp + kf * 32);
#pragma unroll
    for (int db = 0; db < 8; ++db) o[db] = zero4;
#pragma unroll
    for (int i = 0; i < 4; ++i) { mrow[i] = -1e30f; lrow[i] = 0.f; }
  };

  auto writeO = [&](int qb) {
    float linv[4];
#pragma unroll
    for (int i = 0; i < 4; ++i) linv[i] = 1.0f / lrow[i];
#pragma unroll
    for (int db = 0; db < 8; ++db)
#pragma unroll
      for (int i = 0; i < 4; ++i) {
        int q = qb * 64 + w * 16 + g * 4 + i;
        Og[((size_t)(b * 2048 + q)) * 2048 + h * 128 + db * 16 + c15] =
            f2bf(o[db][i] * linv[i]);
      }
  };

  const int qbA = pair, qbB = 31 - pair;
  const int ntA = qbA + 1, ntB = qbB + 1;
  int cur = 0;

  stageTile(0, 0);          // prologue: qbA tile 0
  loadQ(qbA);
  for (int tkv = 0; tkv < ntA; ++tkv) {
    __syncthreads();        // current buf ready (drains loads issued last iter)
    if (tkv + 1 < ntA) stageTile(cur ^ 1, tkv + 1);
    else               stageTile(cur ^ 1, 0);      // first tile of half B
    computeTile(cur, qbA, tkv);
    cur ^= 1;
  }
  writeO(qbA);
  loadQ(qbB);
  for (int tkv = 0; tkv < ntB; ++tkv) {
    __syncthreads();
    if (tkv + 1 < ntB) stageTile(cur ^ 1, tkv + 1);
    computeTile(cur, qbB, tkv);
    cur ^= 1;
  }
  writeO(qbB);
}

extern "C" void kernel_launch(void* const* d_in, const int* in_sizes, int n_in,
                              void* d_out, int out_size, void* d_ws, size_t ws_size,
                              hipStream_t stream) {
  const float* x  = (const float*)d_in[0];
  const float* Wq = (const float*)d_in[1];
  const float* Wk = (const float*)d_in[2];
  const float* Wv = (const float*)d_in[3];
  const float* Wo = (const float*)d_in[4];
  char* p = (char*)d_ws;
  unsigned short* xb    = (unsigned short*)p;                 // 16 MB (reused as Ao)
  unsigned short* wqkvb = (unsigned short*)(p + 16777216);    // 24 MB
  unsigned short* wob   = (unsigned short*)(p + 41943040);    //  8 MB
  unsigned short* Qb    = (unsigned short*)(p + 50331648);    // 16 MB
  unsigned short* Kb    = (unsigned short*)(p + 67108864);    // 16 MB
  unsigned short* Vt    = (unsigned short*)(p + 83886080);    // 16 MB
  float* ctab           = (float*)(p + 100663296);            // 0.5 MB
  float* stab           = (float*)(p + 101187584);            // 0.5 MB -> end 101711872
  unsigned short* Ao = xb;  // xb dead after gemm_qkv

  cvt_all<<<dim3(4096, 5), 256, 0, stream>>>(x, Wq, Wk, Wv, Wo, xb, wqkvb, wob);
  rope_table<<<512, 256, 0, stream>>>(ctab, stab);
  gemm_bt<0><<<dim3(48, 32), 256, 0, stream>>>(xb, wqkvb, Qb, Kb, Vt, 6144, 2048);
  rope_apply<<<2048, 256, 0, stream>>>(Qb, Kb, ctab, stab);
  attn_fwd<<<dim3(16, 32), 256, 0, stream>>>(Qb, Kb, Vt, Ao);
  gemm_bt<1><<<dim3(16, 32), 256, 0, stream>>>(Ao, wob, d_out, nullptr, nullptr, 2048, 2048);
}